// Round 15
// baseline (276.621 us; speedup 1.0000x reference)
//
#include <hip/hip_runtime.h>
#include <hip/hip_bf16.h>
#include <math.h>

// NTXent loss, N=8192 rows, D=128.
// loss = mean_i [ log(sum_{j!=i} exp(2*cos_ij)) - 2*cos_{i,partner} ]
// R24: R22's hipLaunchCooperativeKernel was a silent no-op under graph
// capture (absmax 9.0 == ln(8190) == "output never written"). Same fusion,
// plain launch + software grid barrier: ws counters (memset per launch),
// all-threads __threadfence -> syncthreads -> thread0 ACQ_REL add +
// ACQUIRE spin (s_sleep) -> syncthreads -> __threadfence. Deadlock-free by
// construction: launch_bounds(256,2) caps VGPR at 128 (R21 body: 104) and
// 64KB LDS => exactly 2 blocks/CU => all 512 blocks co-resident.
// Stage 1: wave-autonomous norm (pair per wave, 3 packed shfl-reduces, no
// LDS). Stage 2: R21's proven 21.8us sim body byte-for-byte (fence resets
// the vmcnt ledger). Stage 3: finalize 16 rows/block, one atomic/block.

typedef __attribute__((ext_vector_type(8))) short bf16x8;   // 8 bf16 = 4 VGPRs
typedef __attribute__((ext_vector_type(4))) float f32x4;

#define NROWS 8192
#define DDIM  128
#define BHALF 4096
#define NCG   8                     // col groups
#define CGSZ  1024                  // cols per group
#define CHUNKC 128                  // cols per chunk (32 KB)
#define NBLK  512
// zn scaled by sqrt(2/ln2): acc = (2/ln2)*cos, exp(2cos) = exp2(acc)
#define SQRT_E2S 1.6986435980707531f
#define LN2      0.6931471805599453f
#define EXPDIAG  7.38905609893065f

static __device__ __forceinline__ unsigned short f2bf(float f) {
  unsigned int u = __float_as_uint(f);
  unsigned int r = (u + 0x7fffu + ((u >> 16) & 1u)) >> 16;   // RNE
  return (unsigned short)r;
}

static __device__ __forceinline__ void glds16(const unsigned short* g, unsigned short* l) {
  __builtin_amdgcn_global_load_lds((const __attribute__((address_space(1))) unsigned int*)g,
                                   (__attribute__((address_space(3))) unsigned int*)l,
                                   16, 0, 0);
}

// Software grid barrier: all-thread release fence, block-elected counter,
// acquire spin. Safe iff all NBLK blocks co-resident (guaranteed: 64KB LDS
// + VGPR<=128 => 2 blocks/CU x 256 CU = 512).
static __device__ __forceinline__ void grid_barrier(unsigned int* c) {
  __threadfence();                     // drain stores (vmcnt 0) + L2 wb
  __syncthreads();
  if (threadIdx.x == 0) {
    __hip_atomic_fetch_add(c, 1u, __ATOMIC_ACQ_REL, __HIP_MEMORY_SCOPE_AGENT);
    while (__hip_atomic_load(c, __ATOMIC_ACQUIRE, __HIP_MEMORY_SCOPE_AGENT) < NBLK)
      __builtin_amdgcn_s_sleep(1);
  }
  __syncthreads();
  __threadfence();                     // invalidate caches for all waves
}

// ---- Fused kernel: norm -> barrier -> sim -> barrier -> finalize ---------
__global__ __launch_bounds__(256, 2)
void fused_kernel(const float* __restrict__ zi, const float* __restrict__ zj,
                  unsigned short* __restrict__ zn, float* __restrict__ part,
                  float* __restrict__ pos, unsigned int* __restrict__ ctr,
                  float* __restrict__ out) {
  __shared__ unsigned short lds[2 * CHUNKC * DDIM];  // 64 KB (sim; reused fin)

  const int w    = threadIdx.x >> 6;
  const int lane = threadIdx.x & 63;
  const int l15  = lane & 15;
  const int quad = lane >> 4;

  // ======== Stage 1: norm, wave-autonomous, 2 pairs per wave ==============
  #pragma unroll
  for (int p = 0; p < 2; ++p) {
    int pi = blockIdx.x * 8 + p * 4 + w;             // 512*8 = 4096 pairs
    float2 vi = *(const float2*)(zi + (size_t)pi * DDIM + 2 * lane);
    float2 vj = *(const float2*)(zj + (size_t)pi * DDIM + 2 * lane);
    float ssi = vi.x * vi.x + vi.y * vi.y;
    float ssj = vj.x * vj.x + vj.y * vj.y;
    float d   = vi.x * vj.x + vi.y * vj.y;
    #pragma unroll
    for (int off = 1; off < 64; off <<= 1) {
      ssi += __shfl_xor(ssi, off);
      ssj += __shfl_xor(ssj, off);
      d   += __shfl_xor(d, off);
    }
    float si = SQRT_E2S / fmaxf(sqrtf(ssi), 1e-8f);
    float sj = SQRT_E2S / fmaxf(sqrtf(ssj), 1e-8f);
    unsigned int li = f2bf(vi.x * si), hi_ = f2bf(vi.y * si);
    unsigned int lj = f2bf(vj.x * sj), hj  = f2bf(vj.y * sj);
    ((unsigned int*)(zn + (size_t)pi * DDIM))[lane]           = li | (hi_ << 16);
    ((unsigned int*)(zn + (size_t)(pi + BHALF) * DDIM))[lane] = lj | (hj << 16);
    if (lane == 0) pos[pi] = d * si * sj;            // (2/ln2)*cos(i,i+B)
  }
  if (blockIdx.x == 0 && threadIdx.x == 0) out[0] = 0.0f;

  grid_barrier(&ctr[0]);                             // zn/pos visible

  // ======== Stage 2: sim (R21 structure, single pass) =====================
  {
    const int strip = blockIdx.x >> 3;
    const int cg_   = blockIdx.x & 7;
    const int row_base = strip * 128 + w * 32;
    const int col0     = cg_ * CGSZ;

    // A fragments: issued FIRST (oldest in vmcnt order; ledger clean after
    // the barrier's vmcnt-0 fence), pinned by sched_barrier.
    bf16x8 a[2][4];
    const unsigned short* abase = zn + (size_t)(row_base + l15) * DDIM + quad * 8;
    #pragma unroll
    for (int mi = 0; mi < 2; ++mi)
      #pragma unroll
      for (int kf = 0; kf < 4; ++kf)
        a[mi][kf] = *(const bf16x8*)(abase + mi * 16 * DDIM + kf * 32);
    __builtin_amdgcn_sched_barrier(0);   // pin: A-loads strictly before glds

    const int rq = lane >> 4;            // staging row-within-4
    const int cl = lane & 15;            // 16B slot index

#define STAGE(CH, BUF)                                                         \
    {                                                                          \
      _Pragma("unroll")                                                        \
      for (int i = 0; i < 8; ++i) {                                            \
        int r = (w * 8 + i) * 4 + rq;                                          \
        int c = cl ^ (r & 15);                                                 \
        glds16(zn + (size_t)(col0 + (CH) * CHUNKC + r) * DDIM + c * 8,         \
               lds + (BUF) * (CHUNKC * DDIM) + (w * 8 + i) * 512);             \
      }                                                                        \
    }

    STAGE(0, 0)
    STAGE(1, 1)
    __builtin_amdgcn_sched_barrier(0);   // pin: glds issued before loop body

    int rdoff[4];
    #pragma unroll
    for (int kf = 0; kf < 4; ++kf)
      rdoff[kf] = l15 * DDIM + (((quad + 4 * kf) ^ l15) << 3);

    float rs[2][4];
    #pragma unroll
    for (int mi = 0; mi < 2; ++mi)
      #pragma unroll
      for (int r = 0; r < 4; ++r) rs[mi][r] = 0.0f;

#define COMPUTE(LB)                                                            \
    {                                                                          \
      _Pragma("unroll")                                                        \
      for (int ni = 0; ni < 8; ++ni) {                                         \
        bf16x8 b[4];                                                           \
        _Pragma("unroll")                                                      \
        for (int kf = 0; kf < 4; ++kf)                                         \
          b[kf] = *(const bf16x8*)((LB) + ni * 16 * DDIM + rdoff[kf]);         \
        f32x4 z = {0.0f, 0.0f, 0.0f, 0.0f};                                    \
        f32x4 acc0 = __builtin_amdgcn_mfma_f32_16x16x32_bf16(a[0][0], b[0], z, 0, 0, 0); \
        f32x4 acc1 = __builtin_amdgcn_mfma_f32_16x16x32_bf16(a[1][0], b[0], z, 0, 0, 0); \
        _Pragma("unroll")                                                      \
        for (int kf = 1; kf < 4; ++kf) {                                       \
          acc0 = __builtin_amdgcn_mfma_f32_16x16x32_bf16(a[0][kf], b[kf], acc0, 0, 0, 0); \
          acc1 = __builtin_amdgcn_mfma_f32_16x16x32_bf16(a[1][kf], b[kf], acc1, 0, 0, 0); \
        }                                                                      \
        _Pragma("unroll")                                                      \
        for (int r = 0; r < 4; ++r) {                                          \
          rs[0][r] += __builtin_amdgcn_exp2f(acc0[r]);                         \
          rs[1][r] += __builtin_amdgcn_exp2f(acc1[r]);                         \
        }                                                                      \
      }                                                                        \
    }

    // Phases 0..5: vmcnt(8), compute, barrier, restage. 6: vmcnt(8). 7: 0.
    #pragma unroll 1
    for (int ch = 0; ch < 6; ++ch) {
      asm volatile("s_waitcnt vmcnt(8)" ::: "memory");
      __builtin_amdgcn_s_barrier();
      __builtin_amdgcn_sched_barrier(0);
      const unsigned short* lb = lds + (ch & 1) * (CHUNKC * DDIM);
      COMPUTE(lb)
      __builtin_amdgcn_sched_barrier(0);
      __builtin_amdgcn_s_barrier();
      STAGE(ch + 2, (ch & 1))
    }
    asm volatile("s_waitcnt vmcnt(8)" ::: "memory");
    __builtin_amdgcn_s_barrier();
    __builtin_amdgcn_sched_barrier(0);
    COMPUTE(lds)
    asm volatile("s_waitcnt vmcnt(0)" ::: "memory");
    __builtin_amdgcn_s_barrier();
    __builtin_amdgcn_sched_barrier(0);
    COMPUTE(lds + CHUNKC * DDIM)
#undef COMPUTE
#undef STAGE

    // Row reduce; C/D layout: col=l15, row=quad*4+reg. Disjoint slot cg_.
    #pragma unroll
    for (int mi = 0; mi < 2; ++mi)
      #pragma unroll
      for (int r = 0; r < 4; ++r) {
        float v = rs[mi][r];
        v += __shfl_xor(v, 1);
        v += __shfl_xor(v, 2);
        v += __shfl_xor(v, 4);
        v += __shfl_xor(v, 8);
        if (l15 == 0)
          part[(size_t)cg_ * NROWS + row_base + mi * 16 + quad * 4 + r] = v;
      }
  }

  grid_barrier(&ctr[1]);                             // part visible

  // ======== Stage 3: finalize, 16 rows per block ==========================
  {
    float* fsum = (float*)lds;                       // [4][16], aliased
    int r = blockIdx.x * 16 + l15;                   // 512*16 = 8192 rows
    int k = (threadIdx.x >> 4);                      // 0..15; slots 0..7 live
    float s = (k < NCG) ? part[(size_t)k * NROWS + r] : 0.0f;
    s += __shfl_xor(s, 16);                          // sum this wave's 4 k's
    s += __shfl_xor(s, 32);
    if (lane < 16) fsum[w * 16 + lane] = s;
    __syncthreads();
    if (w == 0 && lane < 16) {
      float tot = fsum[lane] + fsum[16 + lane] + fsum[32 + lane] + fsum[48 + lane];
      // per row: logsumexp(logits) - logits[0] = log(S - e^2) - ln2 * pos
      float v = logf(tot - EXPDIAG) - LN2 * pos[r & (BHALF - 1)];
      v += __shfl_xor(v, 1);
      v += __shfl_xor(v, 2);
      v += __shfl_xor(v, 4);
      v += __shfl_xor(v, 8);
      if (lane == 0) atomicAdd(out, v * (1.0f / 8192.0f));
    }
  }
}

extern "C" void kernel_launch(void* const* d_in, const int* in_sizes, int n_in,
                              void* d_out, int out_size, void* d_ws, size_t ws_size,
                              hipStream_t stream) {
  const float* zi = (const float*)d_in[0];
  const float* zj = (const float*)d_in[1];
  char* ws = (char*)d_ws;
  unsigned short* zn = (unsigned short*)ws;                       // 2 MB
  float* part = (float*)(ws + (size_t)NROWS * DDIM * 2);          // 256 KB (8x8192)
  float* pos  = (float*)(ws + (size_t)NROWS * DDIM * 2
                            + (size_t)NCG * NROWS * 4);           // 16 KB
  unsigned int* ctr = (unsigned int*)(ws + (size_t)NROWS * DDIM * 2
                                         + (size_t)NCG * NROWS * 4
                                         + (size_t)BHALF * 4);    // 8 B
  float* out = (float*)d_out;

  hipMemsetAsync(ctr, 0, 2 * sizeof(unsigned int), stream);       // barrier ctrs
  fused_kernel<<<NBLK, 256, 0, stream>>>(zi, zj, zn, part, pos, ctr, out);
}